// Round 19
// baseline (46.002 us; speedup 1.0000x reference)
//
#include <hip/hip_runtime.h>

// RefCondMul: x[B=4][64][L=8192] f32, inds[B][L] int32, w[1000][64][64] f32,
// bias[1000][1][64] f32 -> out[B][64][L] f32.
// out[b][o][l] = sum_m x[b][m][l] * w[inds[b][l]][m][o] + bias[inds[b][l]][0][o]
//
// R19: 2-node pipeline. k_tin DELETED -- k_main gathers each sample's x
// column DIRECTLY from x (fp32, 64 x 4B at stride 32KB). x is 8MB =
// L3-resident (reads are broadcast-safe; ~128MB line traffic through L2/L3
// ~ 4us, hidden under w HBM staging). Write side keeps the coalescing path
// (ot bf16 -> tout) because scattered 4B stores would partial-line-thrash
// HBM writebacks. vs R17 (32.0us best): -1 launch gap, -tin work, -xt
// round-trip; x no longer bf16-rounded (absmax should drop ~0.0156->~0.008).
// History: R4 54.4 -> R8 39.5 (binning) -> R13 37.3 -> R17 32.0 (bf16
// intermediates) -> R18 null (TLP) -> this.

#define M_DIM 64
#define N_OUTD 64
#define L_DIM 8192
#define B_DIM 4
#define NCLS 1000
#define NSAMP (B_DIM * L_DIM)
#define NSMAX 512   // match-list capacity (>=15 sigma above Poisson(32.8) max)

typedef float    float4v __attribute__((ext_vector_type(4)));
typedef unsigned uint4v  __attribute__((ext_vector_type(4)));
typedef unsigned uint2v  __attribute__((ext_vector_type(2)));
typedef int      int4v   __attribute__((ext_vector_type(4)));

// ---- workspace layout (bytes) ----
#define OT_OFF   0ull            // ot[NSAMP][64] bf16, sample order : 4 MB
#define WS_NEED  4194304ull

// bf16 pack/unpack (RNE round; pair packed little-endian: elem0 = low 16)
__device__ __forceinline__ unsigned rbf(float f) {
  unsigned u = __float_as_uint(f);
  return (u + 0x7fffu + ((u >> 16) & 1u)) >> 16;
}
__device__ __forceinline__ unsigned pk2(float f0, float f1) {
  return rbf(f0) | (rbf(f1) << 16);
}
__device__ __forceinline__ float ulo(unsigned u) { return __uint_as_float(u << 16); }
__device__ __forceinline__ float uhi(unsigned u) { return __uint_as_float(u & 0xffff0000u); }

// ============ kernel 1: self-binning matvec (1000 blocks, 1 per class) ======
// Scans inds (L2-resident, hidden under w HBM loads held in regs), compacts
// match ids into LDS, stages each sample's x column directly from x
// (scattered fp32 reads, L2/L3-served), then: 16 groups x 4 samples, each
// lane 4 outputs; one b128 w-row LDS read feeds 4 samples. Inner FMA order
// identical to R13..R18.
__global__ __launch_bounds__(256) void k_main(
    const float* __restrict__ x, const int* __restrict__ inds,
    const float* __restrict__ w, const float* __restrict__ bias,
    unsigned* __restrict__ ot) {
  __shared__ float wl[4096];        // w[c]: 16 KB
  __shared__ float xs[64][68];      // 64 samples' x, fp32, padded (17.4 KB)
  __shared__ int   ns[NSMAX];       // match ids (2 KB)
  __shared__ int   scnt;

  const int tid = threadIdx.x;
  const int c   = blockIdx.x;

  // issue w[c] loads into registers FIRST (HBM latency hides under inds scan)
  const float* wp = w + (size_t)c * (M_DIM * N_OUTD);
  float4v wr[4];
#pragma unroll
  for (int p = 0; p < 4; ++p)
    wr[p] = *(const float4v*)(wp + (size_t)(p * 256 + tid) * 4);

  if (tid == 0) scnt = 0;
  __syncthreads();

  // scan inds, push matching sample ids (order irrelevant: samples
  // independent; per-sample m-sum order fixed below -> deterministic output)
  const int4v* ip = (const int4v*)inds;   // 8192 int4
  for (int i = tid; i < NSAMP / 4; i += 256) {
    const int4v v = ip[i];
    const int n0 = i * 4;
    if (v.x == c) { int k = atomicAdd(&scnt, 1); if (k < NSMAX) ns[k] = n0; }
    if (v.y == c) { int k = atomicAdd(&scnt, 1); if (k < NSMAX) ns[k] = n0 + 1; }
    if (v.z == c) { int k = atomicAdd(&scnt, 1); if (k < NSMAX) ns[k] = n0 + 2; }
    if (v.w == c) { int k = atomicAdd(&scnt, 1); if (k < NSMAX) ns[k] = n0 + 3; }
  }

  // store w to LDS
#pragma unroll
  for (int p = 0; p < 4; ++p)
    *(float4v*)(&wl[(p * 256 + tid) * 4]) = wr[p];
  __syncthreads();   // ns, scnt, wl ready

  const int count = min(scnt, NSMAX);   // for this input, scnt << NSMAX
  if (count == 0) return;

  const int wid  = tid >> 6;
  const int lane = tid & 63;
  const int G    = wid * 4 + (lane >> 4);   // group 0..15
  const int oi   = (lane & 15) * 4;         // output base (float4)
  const int jb   = G * 4;                   // group's first sample slot
  const int oj2  = (lane & 15) * 2;         // output base in packed uints
  const float4v bv = *(const float4v*)(bias + (size_t)c * N_OUTD + oi);

  for (int s0 = 0; s0 < count; s0 += 64) {
    // stage up to 64 samples: gather x columns directly (scattered 4B reads,
    // 8 per staging thread; x is L3-resident so these are cache-served)
#pragma unroll
    for (int p = 0; p < 2; ++p) {
      const int idx = p * 256 + tid;
      const int row = idx >> 3;             // 0..63 (sample slot)
      const int m0  = (idx & 7) * 8;        // m base
      if (s0 + row < count) {
        const int n = ns[s0 + row];
        const int b = n >> 13;              // L_DIM = 8192
        const int l = n & (L_DIM - 1);
        const float* xb = x + ((size_t)b * M_DIM + m0) * L_DIM + l;
#pragma unroll
        for (int j = 0; j < 8; ++j)
          xs[row][m0 + j] = xb[(size_t)j * L_DIM];
      }
    }
    __syncthreads();

    if (s0 + jb < count) {
      float4v a0 = bv, a1 = bv, a2 = bv, a3 = bv;
#pragma unroll 8
      for (int m = 0; m < M_DIM; ++m) {
        const float4v wv = *(const float4v*)(&wl[m * N_OUTD + oi]);  // shared by 4
        a0 += xs[jb + 0][m] * wv;
        a1 += xs[jb + 1][m] * wv;   // rows beyond count hold garbage; stores guarded
        a2 += xs[jb + 2][m] * wv;
        a3 += xs[jb + 3][m] * wv;
      }
      *(uint2v*)(ot + (size_t)ns[s0 + jb] * 32 + oj2) =
          (uint2v){pk2(a0[0], a0[1]), pk2(a0[2], a0[3])};
      if (s0 + jb + 1 < count)
        *(uint2v*)(ot + (size_t)ns[s0 + jb + 1] * 32 + oj2) =
            (uint2v){pk2(a1[0], a1[1]), pk2(a1[2], a1[3])};
      if (s0 + jb + 2 < count)
        *(uint2v*)(ot + (size_t)ns[s0 + jb + 2] * 32 + oj2) =
            (uint2v){pk2(a2[0], a2[1]), pk2(a2[2], a2[3])};
      if (s0 + jb + 3 < count)
        *(uint2v*)(ot + (size_t)ns[s0 + jb + 3] * 32 + oj2) =
            (uint2v){pk2(a3[0], a3[1]), pk2(a3[2], a3[3])};
    }
    __syncthreads();   // xs reuse guard
  }
}

// ============ kernel 2: streaming transpose-out, bf16 -> fp32 (512 blocks) ==
// out[b][o][l] = fp32(ot[b*L+l][o]); sequential ot reads, 256B out writes.
// (= R17's validated kernel.)
__global__ __launch_bounds__(256) void k_tout(
    const unsigned* __restrict__ ot, float* __restrict__ out) {
  __shared__ float tile[64][68];  // [o][l], padded
  const int tid = threadIdx.x;
  const int b  = blockIdx.x >> 7;
  const int l0 = (blockIdx.x & 127) << 6;
  const size_t nbase = (size_t)(b * L_DIM + l0);

#pragma unroll
  for (int p = 0; p < 2; ++p) {
    const int idx = p * 256 + tid;
    const int row = idx >> 3;              // l within tile
    const int ch  = idx & 7;               // uint4 chunk (8 o-values)
    uint4v u = *(const uint4v*)(ot + (nbase + row) * 32 + ch * 4);  // 128B/row
#pragma unroll
    for (int j = 0; j < 4; ++j) {
      tile[ch * 8 + 2 * j][row]     = ulo(u[j]);
      tile[ch * 8 + 2 * j + 1][row] = uhi(u[j]);
    }
  }
  __syncthreads();
  float* ob = out + ((size_t)b * N_OUTD) * L_DIM + l0;
  const int r  = tid >> 4;
  const int c4 = (tid & 15) * 4;
#pragma unroll
  for (int p = 0; p < 4; ++p) {
    const int o = r + 16 * p;
    float4v v = *(const float4v*)(&tile[o][c4]);
    *(float4v*)(ob + (size_t)o * L_DIM + c4) = v;  // 256B segments
  }
}

// ============ fallback (R4 kernel, pure fp32) if ws too small ===============
#define TL 16
__global__ __launch_bounds__(256) void condmul_fallback(
    const float* __restrict__ x, const int* __restrict__ inds,
    const float* __restrict__ w, const float* __restrict__ bias,
    float* __restrict__ out) {
  __shared__ float xs[M_DIM][TL];
  __shared__ float os[TL][N_OUTD + 4];
  const int tid  = threadIdx.x;
  const int wid  = tid >> 6;
  const int lane = tid & 63;
  const int g    = lane >> 4;
  const int oi   = (lane & 15) * 4;
  const int n0   = blockIdx.x * TL;
  const int b    = n0 / L_DIM;
  const int l0   = n0 % L_DIM;
  {
    const int li = tid & (TL - 1);
    const int m0 = tid >> 4;
    const float* xb = x + ((size_t)b * M_DIM) * L_DIM + l0;
#pragma unroll
    for (int p = 0; p < 4; ++p) {
      const int m = p * 16 + m0;
      xs[m][li] = xb[(size_t)m * L_DIM + li];
    }
  }
  __syncthreads();
  const int li = wid * 4 + g;
  const int c  = inds[n0 + li];
  const float* wp = w + ((size_t)c * M_DIM) * N_OUTD + oi;
  float4v acc = {0.f, 0.f, 0.f, 0.f};
#pragma unroll 8
  for (int m = 0; m < M_DIM; ++m) {
    const float  xv = xs[m][li];
    const float4v wv = *(const float4v*)(wp + (size_t)m * N_OUTD);
    acc += xv * wv;
  }
  acc += *(const float4v*)(bias + (size_t)c * N_OUTD + oi);
  *(float4v*)(&os[li][oi]) = acc;
  __syncthreads();
  {
    const int lo = tid & (TL - 1);
    const int o0 = tid >> 4;
    float* ob = out + ((size_t)b * N_OUTD) * L_DIM + l0;
#pragma unroll
    for (int p = 0; p < 4; ++p) {
      const int o = p * 16 + o0;
      ob[(size_t)o * L_DIM + lo] = os[lo][o];
    }
  }
}

extern "C" void kernel_launch(void* const* d_in, const int* in_sizes, int n_in,
                              void* d_out, int out_size, void* d_ws, size_t ws_size,
                              hipStream_t stream) {
  const float* x    = (const float*)d_in[0];
  const int*   inds = (const int*)d_in[1];
  const float* w    = (const float*)d_in[2];
  const float* bias = (const float*)d_in[3];
  float*       out  = (float*)d_out;

  if (ws_size < WS_NEED) {
    condmul_fallback<<<NSAMP / TL, 256, 0, stream>>>(x, inds, w, bias, out);
    return;
  }

  unsigned* ot = (unsigned*)((char*)d_ws + OT_OFF);

  k_main<<<NCLS, 256, 0, stream>>>(x, inds, w, bias, ot);
  k_tout<<<512, 256, 0, stream>>>(ot, out);
}

// Round 20
// 32.686 us; speedup vs baseline: 1.4074x; 1.4074x over previous
//
#include <hip/hip_runtime.h>

// RefCondMul: x[B=4][64][L=8192] f32, inds[B][L] int32, w[1000][64][64] f32,
// bias[1000][1][64] f32 -> out[B][64][L] f32.
// out[b][o][l] = sum_m x[b][m][l] * w[inds[b][l]][m][o] + bias[inds[b][l]][0][o]
//
// R20 = exact revert to R17 (proven 32.03us best).
// R19 falsified the direct-gather idea with counters: k_main 45us alone,
// FETCH 77.6MB (~10x line-granule amplification; stride-32KB 4B reads thrash
// the 4MB per-XCD L2s; L3 residency does NOT make scattered reads cheap).
// The xt transpose materialization pays x's bytes once, coalesced.
// Structure: tin (512) -> main self-scan binning (1000) -> tout (512),
// bf16 intermediates (xt, ot), fp32 FMA order fixed since R13.
// Lever inventory (all measured): binning pipeline 37.3 (R13); self-scan
// 3-node 37.5 (R16); bf16 intermediates 32.0 (R17); transpose TLP null
// (R18); node-deletion regression (R19); coop grid.sync ~100us/sync (R10);
// column-split main null (R15); LDS-read widening +1.8 (R11->R12 era).

#define M_DIM 64
#define N_OUTD 64
#define L_DIM 8192
#define B_DIM 4
#define NCLS 1000
#define NSAMP (B_DIM * L_DIM)
#define NSMAX 512   // match-list capacity (8x the plausible max class count)

typedef float    float4v __attribute__((ext_vector_type(4)));
typedef unsigned uint4v  __attribute__((ext_vector_type(4)));
typedef unsigned uint2v  __attribute__((ext_vector_type(2)));
typedef int      int4v   __attribute__((ext_vector_type(4)));

// ---- workspace layout (bytes) ----
#define XT_OFF   0ull            // xt[NSAMP][64] bf16, sample order : 4 MB
#define OT_OFF   4194304ull      // ot[NSAMP][64] bf16, sample order : 4 MB
#define WS_NEED  8388608ull

// bf16 pack/unpack (RNE round; pair packed little-endian: elem0 = low 16)
__device__ __forceinline__ unsigned rbf(float f) {
  unsigned u = __float_as_uint(f);
  return (u + 0x7fffu + ((u >> 16) & 1u)) >> 16;
}
__device__ __forceinline__ unsigned pk2(float f0, float f1) {
  return rbf(f0) | (rbf(f1) << 16);
}
__device__ __forceinline__ float ulo(unsigned u) { return __uint_as_float(u << 16); }
__device__ __forceinline__ float uhi(unsigned u) { return __uint_as_float(u & 0xffff0000u); }

// ============ kernel 1: streaming transpose-in, fp32 -> bf16 ================
// xt[n][m] = bf16(x[b][m][l]), n = b*L+l; one 64m x 64l tile per block.
__global__ __launch_bounds__(256) void k_tin(
    const float* __restrict__ x, unsigned* __restrict__ xt) {
  __shared__ float tile[64][68];  // [l][m], padded
  const int tid = threadIdx.x;
  const int b  = blockIdx.x >> 7;
  const int l0 = (blockIdx.x & 127) << 6;

  const float* xb = x + ((size_t)b * M_DIM) * L_DIM + l0;
  const int r  = tid >> 4;         // 0..15
  const int c4 = (tid & 15) * 4;   // 0..60
#pragma unroll
  for (int p = 0; p < 4; ++p) {
    const int m = r + 16 * p;
    float4v v = *(const float4v*)(xb + (size_t)m * L_DIM + c4);  // 256B segs
#pragma unroll
    for (int q = 0; q < 4; ++q) tile[c4 + q][m] = v[q];
  }
  __syncthreads();
  // write bf16 rows: 64 rows x 8 uint4-chunks (8 bf16 = 16B each)
  const size_t nbase = (size_t)(b * L_DIM + l0);
#pragma unroll
  for (int p = 0; p < 2; ++p) {
    const int idx = p * 256 + tid;
    const int row = idx >> 3;        // 0..63 (l within tile)
    const int m0  = (idx & 7) * 8;   // m base
    uint4v u;
#pragma unroll
    for (int j = 0; j < 4; ++j)
      u[j] = pk2(tile[row][m0 + 2 * j], tile[row][m0 + 2 * j + 1]);
    *(uint4v*)(xt + (nbase + row) * 32 + (m0 >> 1)) = u;   // 128B/row
  }
}

// ============ kernel 2: self-binning matvec (1000 blocks, 1 per class) ======
// Scans inds (L2-resident, hidden under w HBM loads held in regs), compacts
// match ids into LDS, then: 16 groups x 4 samples, each lane 4 outputs; one
// b128 w-row LDS read feeds 4 samples. xs staged fp32 (converted on load),
// inner FMA order identical to R13..R18.
__global__ __launch_bounds__(256) void k_main(
    const unsigned* __restrict__ xt, const int* __restrict__ inds,
    const float* __restrict__ w, const float* __restrict__ bias,
    unsigned* __restrict__ ot) {
  __shared__ float wl[4096];        // w[c]: 16 KB
  __shared__ float xs[64][68];      // 64 samples' x, fp32, padded (17.4 KB)
  __shared__ int   ns[NSMAX];       // match ids (2 KB)
  __shared__ int   scnt;

  const int tid = threadIdx.x;
  const int c   = blockIdx.x;

  // issue w[c] loads into registers FIRST (HBM latency hides under inds scan)
  const float* wp = w + (size_t)c * (M_DIM * N_OUTD);
  float4v wr[4];
#pragma unroll
  for (int p = 0; p < 4; ++p)
    wr[p] = *(const float4v*)(wp + (size_t)(p * 256 + tid) * 4);

  if (tid == 0) scnt = 0;
  __syncthreads();

  // scan inds, push matching sample ids (order irrelevant: samples independent)
  const int4v* ip = (const int4v*)inds;   // 8192 int4
  for (int i = tid; i < NSAMP / 4; i += 256) {
    const int4v v = ip[i];
    const int n0 = i * 4;
    if (v.x == c) { int k = atomicAdd(&scnt, 1); if (k < NSMAX) ns[k] = n0; }
    if (v.y == c) { int k = atomicAdd(&scnt, 1); if (k < NSMAX) ns[k] = n0 + 1; }
    if (v.z == c) { int k = atomicAdd(&scnt, 1); if (k < NSMAX) ns[k] = n0 + 2; }
    if (v.w == c) { int k = atomicAdd(&scnt, 1); if (k < NSMAX) ns[k] = n0 + 3; }
  }

  // store w to LDS
#pragma unroll
  for (int p = 0; p < 4; ++p)
    *(float4v*)(&wl[(p * 256 + tid) * 4]) = wr[p];
  __syncthreads();   // ns, scnt, wl ready

  const int count = min(scnt, NSMAX);   // for this input, scnt << NSMAX
  if (count == 0) return;

  const int wid  = tid >> 6;
  const int lane = tid & 63;
  const int G    = wid * 4 + (lane >> 4);   // group 0..15
  const int oi   = (lane & 15) * 4;         // output base (float4)
  const int jb   = G * 4;                   // group's first sample slot
  const int oj2  = (lane & 15) * 2;         // output base in packed uints
  const float4v bv = *(const float4v*)(bias + (size_t)c * N_OUTD + oi);

  for (int s0 = 0; s0 < count; s0 += 64) {
    // stage up to 64 samples: gather bf16 xt rows (128B each), cvt to fp32
#pragma unroll
    for (int p = 0; p < 2; ++p) {
      const int idx = p * 256 + tid;
      const int row = idx >> 3;             // 0..63
      const int ch  = idx & 7;              // uint4 chunk (8 bf16)
      if (s0 + row < count) {
        uint4v u = *(const uint4v*)(xt + (size_t)ns[s0 + row] * 32 + ch * 4);
#pragma unroll
        for (int j = 0; j < 4; ++j) {
          xs[row][ch * 8 + 2 * j]     = ulo(u[j]);
          xs[row][ch * 8 + 2 * j + 1] = uhi(u[j]);
        }
      }
    }
    __syncthreads();

    if (s0 + jb < count) {
      float4v a0 = bv, a1 = bv, a2 = bv, a3 = bv;
#pragma unroll 8
      for (int m = 0; m < M_DIM; ++m) {
        const float4v wv = *(const float4v*)(&wl[m * N_OUTD + oi]);  // shared by 4
        a0 += xs[jb + 0][m] * wv;
        a1 += xs[jb + 1][m] * wv;   // rows beyond count hold garbage; stores guarded
        a2 += xs[jb + 2][m] * wv;
        a3 += xs[jb + 3][m] * wv;
      }
      *(uint2v*)(ot + (size_t)ns[s0 + jb] * 32 + oj2) =
          (uint2v){pk2(a0[0], a0[1]), pk2(a0[2], a0[3])};
      if (s0 + jb + 1 < count)
        *(uint2v*)(ot + (size_t)ns[s0 + jb + 1] * 32 + oj2) =
            (uint2v){pk2(a1[0], a1[1]), pk2(a1[2], a1[3])};
      if (s0 + jb + 2 < count)
        *(uint2v*)(ot + (size_t)ns[s0 + jb + 2] * 32 + oj2) =
            (uint2v){pk2(a2[0], a2[1]), pk2(a2[2], a2[3])};
      if (s0 + jb + 3 < count)
        *(uint2v*)(ot + (size_t)ns[s0 + jb + 3] * 32 + oj2) =
            (uint2v){pk2(a3[0], a3[1]), pk2(a3[2], a3[3])};
    }
    __syncthreads();   // xs reuse guard
  }
}

// ============ kernel 3: streaming transpose-out, bf16 -> fp32 ===============
// out[b][o][l] = fp32(ot[b*L+l][o]); sequential ot reads, 256B out writes.
__global__ __launch_bounds__(256) void k_tout(
    const unsigned* __restrict__ ot, float* __restrict__ out) {
  __shared__ float tile[64][68];  // [o][l], padded
  const int tid = threadIdx.x;
  const int b  = blockIdx.x >> 7;
  const int l0 = (blockIdx.x & 127) << 6;
  const size_t nbase = (size_t)(b * L_DIM + l0);

#pragma unroll
  for (int p = 0; p < 2; ++p) {
    const int idx = p * 256 + tid;
    const int row = idx >> 3;              // l within tile
    const int ch  = idx & 7;               // uint4 chunk (8 o-values)
    uint4v u = *(const uint4v*)(ot + (nbase + row) * 32 + ch * 4);  // 128B/row
#pragma unroll
    for (int j = 0; j < 4; ++j) {
      tile[ch * 8 + 2 * j][row]     = ulo(u[j]);
      tile[ch * 8 + 2 * j + 1][row] = uhi(u[j]);
    }
  }
  __syncthreads();
  float* ob = out + ((size_t)b * N_OUTD) * L_DIM + l0;
  const int r  = tid >> 4;
  const int c4 = (tid & 15) * 4;
#pragma unroll
  for (int p = 0; p < 4; ++p) {
    const int o = r + 16 * p;
    float4v v = *(const float4v*)(&tile[o][c4]);
    *(float4v*)(ob + (size_t)o * L_DIM + c4) = v;  // 256B segments
  }
}

// ============ fallback (R4 kernel, pure fp32) if ws too small ===============
#define TL 16
__global__ __launch_bounds__(256) void condmul_fallback(
    const float* __restrict__ x, const int* __restrict__ inds,
    const float* __restrict__ w, const float* __restrict__ bias,
    float* __restrict__ out) {
  __shared__ float xs[M_DIM][TL];
  __shared__ float os[TL][N_OUTD + 4];
  const int tid  = threadIdx.x;
  const int wid  = tid >> 6;
  const int lane = tid & 63;
  const int g    = lane >> 4;
  const int oi   = (lane & 15) * 4;
  const int n0   = blockIdx.x * TL;
  const int b    = n0 / L_DIM;
  const int l0   = n0 % L_DIM;
  {
    const int li = tid & (TL - 1);
    const int m0 = tid >> 4;
    const float* xb = x + ((size_t)b * M_DIM) * L_DIM + l0;
#pragma unroll
    for (int p = 0; p < 4; ++p) {
      const int m = p * 16 + m0;
      xs[m][li] = xb[(size_t)m * L_DIM + li];
    }
  }
  __syncthreads();
  const int li = wid * 4 + g;
  const int c  = inds[n0 + li];
  const float* wp = w + ((size_t)c * M_DIM) * N_OUTD + oi;
  float4v acc = {0.f, 0.f, 0.f, 0.f};
#pragma unroll 8
  for (int m = 0; m < M_DIM; ++m) {
    const float  xv = xs[m][li];
    const float4v wv = *(const float4v*)(wp + (size_t)m * N_OUTD);
    acc += xv * wv;
  }
  acc += *(const float4v*)(bias + (size_t)c * N_OUTD + oi);
  *(float4v*)(&os[li][oi]) = acc;
  __syncthreads();
  {
    const int lo = tid & (TL - 1);
    const int o0 = tid >> 4;
    float* ob = out + ((size_t)b * N_OUTD) * L_DIM + l0;
#pragma unroll
    for (int p = 0; p < 4; ++p) {
      const int o = p * 16 + o0;
      ob[(size_t)o * L_DIM + lo] = os[lo][o];
    }
  }
}

extern "C" void kernel_launch(void* const* d_in, const int* in_sizes, int n_in,
                              void* d_out, int out_size, void* d_ws, size_t ws_size,
                              hipStream_t stream) {
  const float* x    = (const float*)d_in[0];
  const int*   inds = (const int*)d_in[1];
  const float* w    = (const float*)d_in[2];
  const float* bias = (const float*)d_in[3];
  float*       out  = (float*)d_out;

  if (ws_size < WS_NEED) {
    condmul_fallback<<<NSAMP / TL, 256, 0, stream>>>(x, inds, w, bias, out);
    return;
  }

  char* ws = (char*)d_ws;
  unsigned* xt = (unsigned*)(ws + XT_OFF);
  unsigned* ot = (unsigned*)(ws + OT_OFF);

  k_tin<<<512, 256, 0, stream>>>(x, xt);
  k_main<<<NCLS, 256, 0, stream>>>(xt, inds, w, bias, ot);
  k_tout<<<512, 256, 0, stream>>>(ot, out);
}